// Round 4
// baseline (47.375 us; speedup 1.0000x reference)
//
#include <hip/hip_runtime.h>
#include <stdint.h>

#define IMG_W 384
#define IMG_H 384
#define IMG_PIX (IMG_W * IMG_H)
#define N_IMG 16            // 8 pred images + 8 target images
#define SENT 0x7fff         // u16 sentinel: no seed in this row
#define BIGI (1 << 28)      // int sentinel for "no seed found"
#define COL_BLOCKS 1024
#define PIX_PER_BLK (N_IMG * IMG_PIX / COL_BLOCKS)  // 2304 = 6 rows
#define PIX_PER_THR (PIX_PER_BLK / 256)             // 9
#define BLKS_PER_IMG (IMG_PIX / PIX_PER_BLK)        // 64

// ---------------------------------------------------------------------------
// nearest set bit distance within a 384-bit mask held as 6 u64 words.
__device__ __forceinline__ int nearest_bit_dist(const unsigned long long m[6],
                                                int wp, int b) {
    const int BIG = 1 << 20;
    int best = BIG;
    unsigned long long t = m[wp] >> b;
    if (t) best = __builtin_ctzll(t);
#pragma unroll
    for (int w = 0; w < 6; ++w) {
        if (w > wp && m[w]) {
            int cand = ((w - wp) << 6) - b + __builtin_ctzll(m[w]);
            best = min(best, cand);
        }
    }
    unsigned long long u = m[wp] << (63 - b);
    if (u) best = min(best, (int)__builtin_clzll(u));
#pragma unroll
    for (int w = 0; w < 6; ++w) {
        if (w < wp && m[w]) {
            int cand = ((wp - w - 1) << 6) + b + 1 + __builtin_clzll(m[w]);
            best = min(best, cand);
        }
    }
    return best;
}

// ---------------------------------------------------------------------------
// Row pass: one wave per row. Per-row flag written UNCONDITIONALLY (so no
// zero-init kernel is needed; ws poison is overwritten every launch).
// Block 0 also zeroes the colpass completion counter — safe because stream
// ordering guarantees rowpass fully retires before colpass starts.
__global__ __launch_bounds__(256) void k_rowpass(const float* __restrict__ pred,
                                                 const float* __restrict__ target,
                                                 uint32_t* __restrict__ d1,
                                                 int* __restrict__ rowflags,
                                                 int* __restrict__ counter) {
    if (blockIdx.x == 0 && threadIdx.x == 0) *counter = 0;

    int wave = threadIdx.x >> 6;
    int lane = threadIdx.x & 63;
    int row  = blockIdx.x * 4 + wave;        // 0 .. 6143
    int img  = row / IMG_H;                  // 0 .. 15
    int x    = row - img * IMG_H;
    const float* src = (img < 8) ? (pred + img * IMG_PIX)
                                 : (target + (img - 8) * IMG_PIX);
    const float* rp = src + x * IMG_W;

    unsigned long long mf[6], mb[6];
    bool any_fg = false;
#pragma unroll
    for (int j = 0; j < 6; ++j) {
        float v = rp[lane + 64 * j];
        mf[j] = __ballot(v == 1.0f);
        mb[j] = ~mf[j];
        any_fg = any_fg || (mf[j] != 0ull);
    }
    if (lane == 0) rowflags[row] = any_fg ? 1 : 0;

    uint32_t* dst = d1 + row * IMG_W;
#pragma unroll
    for (int j = 0; j < 6; ++j) {
        int kf = nearest_bit_dist(mf, j, lane);
        int kb = nearest_bit_dist(mb, j, lane);
        uint32_t ef = (kf > SENT) ? SENT : (uint32_t)kf;
        uint32_t eb = (kb > SENT) ? SENT : (uint32_t)kb;
        dst[lane + 64 * j] = ef | (eb << 16);
    }
}

// ---------------------------------------------------------------------------
// Column pass + fused loss + final reduction. 1024 blocks, each owning 2304
// consecutive pixels of exactly one image (147456/2304 = 64 blocks/image).
// Image has_fg derived by OR-reducing the image's 384 row flags. Last block
// to finish (ticket counter) reduces the 1024 partials and writes the loss.
__global__ __launch_bounds__(256) void k_colpass(const float* __restrict__ pred,
                                                 const float* __restrict__ target,
                                                 const uint32_t* __restrict__ d1,
                                                 const int* __restrict__ rowflags,
                                                 float* __restrict__ partials,
                                                 int* __restrict__ counter,
                                                 float* __restrict__ out) {
    int img   = blockIdx.x >> 6;             // / BLKS_PER_IMG
    int chunk = blockIdx.x & (BLKS_PER_IMG - 1);
    int lane  = threadIdx.x & 63;

    // image-level has_fg from per-row flags (6 coalesced loads per lane)
    const int* rf = rowflags + img * IMG_H;
    int any = 0;
#pragma unroll
    for (int j = 0; j < 6; ++j) any |= rf[lane + 64 * j];
    bool flag = __any(any != 0);

    float contrib = 0.0f;
    if (flag) {
        const uint32_t* d = d1 + img * IMG_PIX;
        const float* pp = pred   + (img & 7) * IMG_PIX;
        const float* tp = target + (img & 7) * IMG_PIX;
#pragma unroll
        for (int i = 0; i < PIX_PER_THR; ++i) {
            int pid = chunk * PIX_PER_BLK + threadIdx.x + 256 * i; // in-image
            int x = pid / IMG_W;
            int y = pid - x * IMG_W;
            float pv = pp[pid];
            float tv = tp[pid];

            uint32_t c = d[pid];
            int kf = (int)(c & 0xffffu), kb = (int)(c >> 16);
            int bf = (kf >= SENT) ? BIGI : kf * kf;
            int bb = (kb >= SENT) ? BIGI : kb * kb;
            int k = 1, kk = 1;
            while ((kk < bf || kk < bb) && k < IMG_H) {
                int xm = x - k, xp = x + k;
                if (xm >= 0) {
                    uint32_t cc = d[xm * IMG_W + y];
                    int f = (int)(cc & 0xffffu), b2 = (int)(cc >> 16);
                    if (f  < SENT) bf = min(bf, f * f + kk);
                    if (b2 < SENT) bb = min(bb, b2 * b2 + kk);
                }
                if (xp < IMG_H) {
                    uint32_t cc = d[xp * IMG_W + y];
                    int f = (int)(cc & 0xffffu), b2 = (int)(cc >> 16);
                    if (f  < SENT) bf = min(bf, f * f + kk);
                    if (b2 < SENT) bb = min(bb, b2 * b2 + kk);
                }
                ++k;
                kk = k * k;
            }
            float dbf = (bf >= BIGI) ? 1e12f : (float)bf;
            float dbb = (bb >= BIGI) ? 1e12f : (float)bb;
            float e = pv - tv;
            contrib += e * e * (dbf + dbb);   // field^2 (one term always 0)
        }
    }

    // block reduction
    for (int o = 32; o > 0; o >>= 1) contrib += __shfl_down(contrib, o);
    __shared__ float part[4];
    __shared__ int is_last;
    int wv = threadIdx.x >> 6;
    if (lane == 0) part[wv] = contrib;
    __syncthreads();
    if (threadIdx.x == 0) {
        partials[blockIdx.x] = part[0] + part[1] + part[2] + part[3];
        __threadfence();                       // partial visible device-wide
        int t = atomicAdd(counter, 1);
        is_last = (t == COL_BLOCKS - 1) ? 1 : 0;
    }
    __syncthreads();

    if (is_last) {
        __threadfence();                       // acquire side
        double s = 0.0;
        for (int i = threadIdx.x; i < COL_BLOCKS; i += 256)
            s += (double)partials[i];
        for (int o = 32; o > 0; o >>= 1) s += __shfl_down(s, o);
        __shared__ double dpart[4];
        if (lane == 0) dpart[wv] = s;
        __syncthreads();
        if (threadIdx.x == 0)
            out[0] = (float)((dpart[0] + dpart[1] + dpart[2] + dpart[3]) *
                             (1.0 / (double)(8 * IMG_PIX)));
    }
}

// ---------------------------------------------------------------------------
extern "C" void kernel_launch(void* const* d_in, const int* in_sizes, int n_in,
                              void* d_out, int out_size, void* d_ws, size_t ws_size,
                              hipStream_t stream) {
    const float* pred   = (const float*)d_in[0];
    const float* target = (const float*)d_in[1];
    char* ws = (char*)d_ws;
    int*      counter  = (int*)ws;                   // 4 B
    int*      rowflags = (int*)(ws + 128);           // 6144 ints = 24 KB
    float*    partials = (float*)(ws + 32768);       // 1024 floats
    uint32_t* d1       = (uint32_t*)(ws + 65536);    // 9.44 MB

    k_rowpass<<<N_IMG * IMG_H / 4, 256, 0, stream>>>(pred, target, d1,
                                                     rowflags, counter);
    k_colpass<<<COL_BLOCKS, 256, 0, stream>>>(pred, target, d1, rowflags,
                                              partials, counter, (float*)d_out);
}

// Round 5
// 33.058 us; speedup vs baseline: 1.4331x; 1.4331x over previous
//
#include <hip/hip_runtime.h>
#include <stdint.h>

#define IMG_W 384
#define IMG_H 384
#define IMG_PIX (IMG_W * IMG_H)
#define N_IMG 16            // 8 pred images + 8 target images
#define SENT 0x7fff         // u16 sentinel: no seed in this row
#define BIGI (1 << 28)      // int sentinel for "no seed found"
#define CELLS 64            // spread accumulator cells (1 cacheline each -> parallel)

// ---------------------------------------------------------------------------
// nearest set bit distance within a 384-bit mask held as 6 u64 words.
__device__ __forceinline__ int nearest_bit_dist(const unsigned long long m[6],
                                                int wp, int b) {
    const int BIG = 1 << 20;
    int best = BIG;
    unsigned long long t = m[wp] >> b;
    if (t) best = __builtin_ctzll(t);
#pragma unroll
    for (int w = 0; w < 6; ++w) {
        if (w > wp && m[w]) {
            int cand = ((w - wp) << 6) - b + __builtin_ctzll(m[w]);
            best = min(best, cand);
        }
    }
    unsigned long long u = m[wp] << (63 - b);
    if (u) best = min(best, (int)__builtin_clzll(u));
#pragma unroll
    for (int w = 0; w < 6; ++w) {
        if (w < wp && m[w]) {
            int cand = ((wp - w - 1) << 6) + b + 1 + __builtin_clzll(m[w]);
            best = min(best, cand);
        }
    }
    return best;
}

// ---------------------------------------------------------------------------
// Row pass: one wave per row. Per-row flag written UNCONDITIONALLY (no init
// kernel needed). Block 0 zeroes the 64 accumulator cells (stream order
// guarantees rowpass retires before colpass starts). No atomics anywhere.
__global__ __launch_bounds__(256) void k_rowpass(const float* __restrict__ pred,
                                                 const float* __restrict__ target,
                                                 uint32_t* __restrict__ d1,
                                                 int* __restrict__ rowflags,
                                                 double* __restrict__ cells) {
    if (blockIdx.x == 0 && threadIdx.x < CELLS) cells[threadIdx.x] = 0.0;

    int wave = threadIdx.x >> 6;
    int lane = threadIdx.x & 63;
    int row  = blockIdx.x * 4 + wave;        // 0 .. 6143
    int img  = row / IMG_H;                  // 0 .. 15
    int x    = row - img * IMG_H;
    const float* src = (img < 8) ? (pred + img * IMG_PIX)
                                 : (target + (img - 8) * IMG_PIX);
    const float* rp = src + x * IMG_W;

    unsigned long long mf[6], mb[6];
    bool any_fg = false;
#pragma unroll
    for (int j = 0; j < 6; ++j) {
        float v = rp[lane + 64 * j];
        mf[j] = __ballot(v == 1.0f);
        mb[j] = ~mf[j];
        any_fg = any_fg || (mf[j] != 0ull);
    }
    if (lane == 0) rowflags[row] = any_fg ? 1 : 0;

    uint32_t* dst = d1 + row * IMG_W;
#pragma unroll
    for (int j = 0; j < 6; ++j) {
        int kf = nearest_bit_dist(mf, j, lane);
        int kb = nearest_bit_dist(mb, j, lane);
        uint32_t ef = (kf > SENT) ? SENT : (uint32_t)kf;
        uint32_t eb = (kb > SENT) ? SENT : (uint32_t)kb;
        dst[lane + 64 * j] = ef | (eb << 16);
    }
}

// ---------------------------------------------------------------------------
// Column pass + fused loss. 1 pixel/thread (max TLP). Rows x+-1, x+-2 are
// preloaded unconditionally (independent loads -> single L2 round trip;
// clamped duplicate rows can never win the min, so exactness holds); the
// data-dependent loop starts at k=3 and almost never runs. Block partial
// goes to one of 64 spread cells (72 atomics/cell, parallel across cells).
__global__ __launch_bounds__(256) void k_colpass(const float* __restrict__ pred,
                                                 const float* __restrict__ target,
                                                 const uint32_t* __restrict__ d1,
                                                 const int* __restrict__ rowflags,
                                                 double* __restrict__ cells) {
    const int BLOCKS_PER_IMG = IMG_PIX / 256;   // 576
    int img = blockIdx.x / BLOCKS_PER_IMG;
    int pid = (blockIdx.x % BLOCKS_PER_IMG) * 256 + threadIdx.x;
    int lane = threadIdx.x & 63;

    // image-level has_fg from per-row flags (L1-resident after first block)
    const int* rf = rowflags + img * IMG_H;
    int any = 0;
#pragma unroll
    for (int j = 0; j < 6; ++j) any |= rf[lane + 64 * j];
    bool flag = __any(any != 0);

    float contrib = 0.0f;
    if (flag) {
        int x = pid / IMG_W;
        int y = pid - x * IMG_W;
        int off = (img & 7) * IMG_PIX + pid;   // same (b,c,x,y) in pred/target
        float pv = pred[off];
        float tv = target[off];

        const uint32_t* d = d1 + img * IMG_PIX;
        uint32_t c0 = d[pid];
        int xm1 = (x > 0) ? x - 1 : 0;
        int xp1 = (x < IMG_H - 1) ? x + 1 : IMG_H - 1;
        int xm2 = (x > 1) ? x - 2 : 0;
        int xp2 = (x < IMG_H - 2) ? x + 2 : IMG_H - 1;
        uint32_t cm1 = d[xm1 * IMG_W + y];
        uint32_t cp1 = d[xp1 * IMG_W + y];
        uint32_t cm2 = d[xm2 * IMG_W + y];
        uint32_t cp2 = d[xp2 * IMG_W + y];

        int f0 = (int)(c0 & 0xffffu), b0 = (int)(c0 >> 16);
        int bf = (f0 >= SENT) ? BIGI : f0 * f0;
        int bb = (b0 >= SENT) ? BIGI : b0 * b0;
        auto acc = [&](uint32_t cc, int kk) {
            int f = (int)(cc & 0xffffu), b = (int)(cc >> 16);
            if (f < SENT) bf = min(bf, f * f + kk);
            if (b < SENT) bb = min(bb, b * b + kk);
        };
        acc(cm1, 1); acc(cp1, 1); acc(cm2, 4); acc(cp2, 4);

        int k = 3, kk = 9;
        while ((kk < bf || kk < bb) && k < IMG_H) {
            int xm = x - k, xp = x + k;
            if (xm >= 0)    acc(d[xm * IMG_W + y], kk);
            if (xp < IMG_H) acc(d[xp * IMG_W + y], kk);
            ++k;
            kk = k * k;
        }
        float dbf = (bf >= BIGI) ? 1e12f : (float)bf;
        float dbb = (bb >= BIGI) ? 1e12f : (float)bb;
        float e = pv - tv;
        contrib = e * e * (dbf + dbb);        // field^2 (one term always 0)
    }

    // block reduction, then one spread-cell atomic per (nonzero) block
    for (int o = 32; o > 0; o >>= 1) contrib += __shfl_down(contrib, o);
    __shared__ float part[4];
    int wv = threadIdx.x >> 6;
    if (lane == 0) part[wv] = contrib;
    __syncthreads();
    if (threadIdx.x == 0) {
        float s = part[0] + part[1] + part[2] + part[3];
        if (s != 0.0f) atomicAdd(&cells[blockIdx.x & (CELLS - 1)], (double)s);
    }
}

// ---------------------------------------------------------------------------
// final: one wave sums the 64 cells and writes the mean.
__global__ void k_final(const double* __restrict__ cells,
                        float* __restrict__ out) {
    double s = cells[threadIdx.x];
    for (int o = 32; o > 0; o >>= 1) s += __shfl_down(s, o);
    if (threadIdx.x == 0)
        out[0] = (float)(s * (1.0 / (double)(8 * IMG_PIX)));
}

// ---------------------------------------------------------------------------
extern "C" void kernel_launch(void* const* d_in, const int* in_sizes, int n_in,
                              void* d_out, int out_size, void* d_ws, size_t ws_size,
                              hipStream_t stream) {
    const float* pred   = (const float*)d_in[0];
    const float* target = (const float*)d_in[1];
    char* ws = (char*)d_ws;
    double*   cells    = (double*)ws;                // 64 * 8 B
    int*      rowflags = (int*)(ws + 4096);          // 6144 ints = 24 KB
    uint32_t* d1       = (uint32_t*)(ws + 65536);    // 9.44 MB

    k_rowpass<<<N_IMG * IMG_H / 4, 256, 0, stream>>>(pred, target, d1,
                                                     rowflags, cells);
    k_colpass<<<N_IMG * (IMG_PIX / 256), 256, 0, stream>>>(pred, target, d1,
                                                           rowflags, cells);
    k_final  <<<1, 64, 0, stream>>>(cells, (float*)d_out);
}